// Round 9
// baseline (749.036 us; speedup 1.0000x reference)
//
#include <hip/hip_runtime.h>

#define NN 100000
#define NE 1600000
#define IN_DIM 16
#define MSG_DIM 128
#define DT_C 0.1f
#define EPS_C 1e-8f
#define BKT 128                          // dst-nodes per bucket
#define NB ((NN + BKT - 1) / BKT)        // 782 buckets
#define EPB 6400                         // edges per bucketing block
#define NBB (NE / EPB)                   // 250 (exact)
#define EPT (EPB / 256)                  // 25 edges per thread
#define PAD 17                           // LDS row stride (bank-conflict-free)

// Wc = W_msg @ W_out (16x16), bc = b_msg @ W_out (16)
__global__ void compute_wc_kernel(const float* __restrict__ W_msg,
                                  const float* __restrict__ b_msg,
                                  const float* __restrict__ W_out,
                                  float* __restrict__ Wc,
                                  float* __restrict__ bc) {
    int t = threadIdx.x;            // 256 threads
    int i = t >> 4, j = t & 15;
    float s = 0.f;
    for (int k = 0; k < MSG_DIM; ++k)
        s += W_msg[i * MSG_DIM + k] * W_out[k * IN_DIM + j];
    Wc[t] = s;
    if (t < IN_DIM) {
        float sb = 0.f;
        for (int k = 0; k < MSG_DIM; ++k)
            sb += b_msg[k] * W_out[k * IN_DIM + t];
        bc[t] = sb;
    }
}

// Per-bucket histogram: LDS-count then one global atomic per (block, bucket).
__global__ __launch_bounds__(256) void hist782_kernel(const int* __restrict__ dst,
                                                      int* __restrict__ bcnt) {
    __shared__ int lc[NB];
    int t = threadIdx.x;
    for (int j = t; j < NB; j += 256) lc[j] = 0;
    __syncthreads();
    int base = blockIdx.x * EPB + t;
    #pragma unroll
    for (int it = 0; it < EPT; ++it) {
        int d = dst[base + it * 256];
        atomicAdd(&lc[d >> 7], 1);
    }
    __syncthreads();
    for (int j = t; j < NB; j += 256) {
        int c = lc[j];
        if (c) atomicAdd(&bcnt[j], c);
    }
}

// Exclusive scan of the 782 bucket counts (single block).
__global__ __launch_bounds__(1024) void scan782_kernel(const int* __restrict__ bcnt,
                                                       int* __restrict__ gbase,
                                                       int* __restrict__ gcur) {
    __shared__ int sh[1024];
    int t = threadIdx.x;
    int v = (t < NB) ? bcnt[t] : 0;
    sh[t] = v;
    __syncthreads();
    #pragma unroll
    for (int off = 1; off < 1024; off <<= 1) {
        int u = (t >= off) ? sh[t - off] : 0;
        __syncthreads();
        sh[t] += u;
        __syncthreads();
    }
    if (t < NB) {
        int ex = sh[t] - v;
        gbase[t] = ex;
        gcur[t] = ex;
    }
    if (t == 0) gbase[NB] = NE;
}

// Bucketing pass: partition edges by dst-bucket into packed entries
// (d_local<<17 | src). LDS per-bucket count, one global reserve atomic per
// (block,bucket) (~195K total), then ~8-entry contiguous runs per bucket.
__global__ __launch_bounds__(256) void bucketA_kernel(const int* __restrict__ src,
                                                      const int* __restrict__ dst,
                                                      int* __restrict__ gcur,
                                                      unsigned* __restrict__ bucket) {
    __shared__ int lcnt[NB];
    __shared__ int lbase[NB];
    int t = threadIdx.x;
    for (int j = t; j < NB; j += 256) lcnt[j] = 0;
    __syncthreads();

    int d[EPT], s[EPT];
    int base = blockIdx.x * EPB + t;
    #pragma unroll
    for (int it = 0; it < EPT; ++it) {
        d[it] = dst[base + it * 256];
        s[it] = src[base + it * 256];
    }
    #pragma unroll
    for (int it = 0; it < EPT; ++it) atomicAdd(&lcnt[d[it] >> 7], 1);
    __syncthreads();
    for (int j = t; j < NB; j += 256) {
        int c = lcnt[j];
        lbase[j] = c ? atomicAdd(&gcur[j], c) : 0;
        lcnt[j] = 0;                // reuse as local cursor
    }
    __syncthreads();
    #pragma unroll
    for (int it = 0; it < EPT; ++it) {
        int b = d[it] >> 7;
        int slot = atomicAdd(&lcnt[b], 1);
        bucket[lbase[b] + slot] = ((unsigned)(d[it] & 127) << 17) | (unsigned)s[it];
    }
}

// Fused step: one block per 128-node bucket. Stream the bucket's contiguous
// edge slice (edge-parallel, 4 lanes per edge), gather x[src] (float4),
// accumulate into LDS agg tile via ds_add_f32; then per-node 16x16 matvec +
// Euler + pol renorm + store. No CSR, no global scatter, balanced edge loop.
// xin != xout required (gather reads neighbor rows).
__global__ __launch_bounds__(256) void step_lds_kernel(const float4* __restrict__ x4in,
                                                       const unsigned* __restrict__ bucket,
                                                       const int* __restrict__ gbase,
                                                       const float* __restrict__ Wc,
                                                       const float* __restrict__ bc,
                                                       const float* __restrict__ b_out,
                                                       float4* __restrict__ x4out) {
    __shared__ float agg[BKT * PAD];    // 128 x 17 floats, pad kills bank conflicts
    __shared__ int   ldeg[BKT];
    __shared__ float sWc[256];
    __shared__ float sbc[16];
    __shared__ float sb[16];
    int t = threadIdx.x;
    sWc[t] = Wc[t];
    if (t < 16) { sbc[t] = bc[t]; sb[t] = b_out[t]; }
    for (int j = t; j < BKT * PAD; j += 256) agg[j] = 0.f;
    if (t < BKT) ldeg[t] = 0;
    __syncthreads();

    int b = blockIdx.x;
    int e0 = gbase[b], e1 = gbase[b + 1];
    int q = t & 3;

    for (int i = e0 + (t >> 2); i < e1; i += 64) {
        unsigned p = bucket[i];
        int s  = (int)(p & 0x1FFFFu);
        int dl = (int)(p >> 17);
        float4 v = x4in[s * 4 + q];
        float* a = &agg[dl * PAD + q * 4];
        atomicAdd(a + 0, v.x);
        atomicAdd(a + 1, v.y);
        atomicAdd(a + 2, v.z);
        atomicAdd(a + 3, v.w);
        if (q == 0) atomicAdd(&ldeg[dl], 1);
    }
    __syncthreads();

    if (t < BKT) {
        int n = b * BKT + t;
        if (n < NN) {
            float a[16];
            #pragma unroll
            for (int k = 0; k < 16; ++k) a[k] = agg[t * PAD + k];
            float dg = (float)ldeg[t];

            float o[16];
            #pragma unroll
            for (int j = 0; j < 16; ++j) o[j] = dg * sbc[j] + sb[j];
            #pragma unroll
            for (int k = 0; k < 16; ++k) {
                float ak = a[k];
                #pragma unroll
                for (int j = 0; j < 16; ++j) o[j] = fmaf(ak, sWc[k * 16 + j], o[j]);
            }

            float xn[16];
            const float4* xp = x4in + (size_t)n * 4;
            #pragma unroll
            for (int j4 = 0; j4 < 4; ++j4) {
                float4 xv = xp[j4];
                xn[j4 * 4 + 0] = xv.x + DT_C * o[j4 * 4 + 0];
                xn[j4 * 4 + 1] = xv.y + DT_C * o[j4 * 4 + 1];
                xn[j4 * 4 + 2] = xv.z + DT_C * o[j4 * 4 + 2];
                xn[j4 * 4 + 3] = xv.w + DT_C * o[j4 * 4 + 3];
            }

            float ss = xn[3] * xn[3] + xn[4] * xn[4] + xn[5] * xn[5] + xn[6] * xn[6];
            float sc = 1.0f / fmaxf(sqrtf(ss), EPS_C);
            xn[3] *= sc; xn[4] *= sc; xn[5] *= sc; xn[6] *= sc;

            float4* op = x4out + (size_t)n * 4;
            #pragma unroll
            for (int j4 = 0; j4 < 4; ++j4)
                op[j4] = make_float4(xn[j4 * 4 + 0], xn[j4 * 4 + 1],
                                     xn[j4 * 4 + 2], xn[j4 * 4 + 3]);
        }
    }
}

extern "C" void kernel_launch(void* const* d_in, const int* in_sizes, int n_in,
                              void* d_out, int out_size, void* d_ws, size_t ws_size,
                              hipStream_t stream) {
    const float* x0    = (const float*)d_in[0];
    const int*   ei    = (const int*)d_in[1];   // (2, NE): row0=src, row1=dst
    const float* W_msg = (const float*)d_in[2];
    const float* b_msg = (const float*)d_in[3];
    const float* W_out = (const float*)d_in[4];
    const float* b_out = (const float*)d_in[5];

    float* X = (float*)d_out;                   // final state buffer (ping-pong B1)

    // ws layout: Y (NN*16 f, 6.4MB), bucket (NE u32, 6.4MB, persists across
    // steps), bcnt (NB), gbase (NB+1), gcur (NB), Wc (256), bc (16)
    float*    Y      = (float*)d_ws;
    unsigned* bucket = (unsigned*)(Y + (size_t)NN * IN_DIM);
    int*      bcnt   = (int*)(bucket + NE);
    int*      gbase  = bcnt + NB;
    int*      gcur   = gbase + NB + 1;
    float*    Wc     = (float*)(gcur + NB);
    float*    bc     = Wc + 256;

    const int* src = ei;
    const int* dst = ei + NE;

    compute_wc_kernel<<<1, 256, 0, stream>>>(W_msg, b_msg, W_out, Wc, bc);
    (void)hipMemsetAsync(bcnt, 0, (size_t)NB * sizeof(int), stream);
    hist782_kernel<<<NBB, 256, 0, stream>>>(dst, bcnt);
    scan782_kernel<<<1, 1024, 0, stream>>>(bcnt, gbase, gcur);
    bucketA_kernel<<<NBB, 256, 0, stream>>>(src, dst, gcur, bucket);

    // 4 steps, ping-pong: x0 -> Y -> X -> Y -> X (final lands in d_out)
    const float* bufs_in[4]  = { x0, Y, X, Y };
    float*       bufs_out[4] = { Y,  X, Y, X };
    for (int s = 0; s < 4; ++s) {
        step_lds_kernel<<<NB, 256, 0, stream>>>(
            (const float4*)bufs_in[s], bucket, gbase, Wc, bc, b_out,
            (float4*)bufs_out[s]);
    }
}

// Round 10
// 195.484 us; speedup vs baseline: 3.8317x; 3.8317x over previous
//
#include <hip/hip_runtime.h>

#define NN 100000
#define NE 1600000
#define IN_DIM 16
#define MSG_DIM 128
#define DT_C 0.1f
#define EPS_C 1e-8f
#define BKT 128                          // dst-nodes per bucket
#define NB ((NN + BKT - 1) / BKT)        // 782 buckets
#define EPB 6400                         // edges per bucketing block
#define NBB (NE / EPB)                   // 250 (exact)
#define EPT (EPB / 256)                  // 25 edges per thread
#define CAP 2560                         // LDS csr-slice capacity (mean 2048, sd 45)

// Wc = W_msg @ W_out (16x16), bc = b_msg @ W_out (16)
__global__ void compute_wc_kernel(const float* __restrict__ W_msg,
                                  const float* __restrict__ b_msg,
                                  const float* __restrict__ W_out,
                                  float* __restrict__ Wc,
                                  float* __restrict__ bc) {
    int t = threadIdx.x;            // 256 threads
    int i = t >> 4, j = t & 15;
    float s = 0.f;
    for (int k = 0; k < MSG_DIM; ++k)
        s += W_msg[i * MSG_DIM + k] * W_out[k * IN_DIM + j];
    Wc[t] = s;
    if (t < IN_DIM) {
        float sb = 0.f;
        for (int k = 0; k < MSG_DIM; ++k)
            sb += b_msg[k] * W_out[k * IN_DIM + t];
        bc[t] = sb;
    }
}

// Per-bucket histogram: LDS-count then one global atomic per (block, bucket).
__global__ __launch_bounds__(256) void hist782_kernel(const int* __restrict__ dst,
                                                      int* __restrict__ bcnt) {
    __shared__ int lc[NB];
    int t = threadIdx.x;
    for (int j = t; j < NB; j += 256) lc[j] = 0;
    __syncthreads();
    int base = blockIdx.x * EPB + t;
    #pragma unroll
    for (int it = 0; it < EPT; ++it) {
        int d = dst[base + it * 256];
        atomicAdd(&lc[d >> 7], 1);
    }
    __syncthreads();
    for (int j = t; j < NB; j += 256) {
        int c = lc[j];
        if (c) atomicAdd(&bcnt[j], c);
    }
}

// Exclusive scan of the 782 bucket counts (single block); also offs[NN]=NE.
__global__ __launch_bounds__(1024) void scan782_kernel(const int* __restrict__ bcnt,
                                                       int* __restrict__ gbase,
                                                       int* __restrict__ gcur,
                                                       int* __restrict__ offs) {
    __shared__ int sh[1024];
    int t = threadIdx.x;
    int v = (t < NB) ? bcnt[t] : 0;
    sh[t] = v;
    __syncthreads();
    #pragma unroll
    for (int off = 1; off < 1024; off <<= 1) {
        int u = (t >= off) ? sh[t - off] : 0;
        __syncthreads();
        sh[t] += u;
        __syncthreads();
    }
    if (t < NB) {
        int ex = sh[t] - v;
        gbase[t] = ex;
        gcur[t] = ex;
    }
    if (t == 0) { gbase[NB] = NE; offs[NN] = NE; }
}

// Bucketing pass: partition edges by dst-bucket into packed (d_local<<17|src)
// entries. LDS per-bucket count, one global reserve atomic per (block,bucket),
// ~8-entry contiguous runs -> coalesced; edge arrays read exactly once.
__global__ __launch_bounds__(256) void bucketA_kernel(const int* __restrict__ src,
                                                      const int* __restrict__ dst,
                                                      int* __restrict__ gcur,
                                                      unsigned* __restrict__ bucket) {
    __shared__ int lcnt[NB];
    __shared__ int lbase[NB];
    int t = threadIdx.x;
    for (int j = t; j < NB; j += 256) lcnt[j] = 0;
    __syncthreads();

    int d[EPT], s[EPT];
    int base = blockIdx.x * EPB + t;
    #pragma unroll
    for (int it = 0; it < EPT; ++it) {
        d[it] = dst[base + it * 256];
        s[it] = src[base + it * 256];
    }
    #pragma unroll
    for (int it = 0; it < EPT; ++it) atomicAdd(&lcnt[d[it] >> 7], 1);
    __syncthreads();
    for (int j = t; j < NB; j += 256) {
        int c = lcnt[j];
        lbase[j] = c ? atomicAdd(&gcur[j], c) : 0;
        lcnt[j] = 0;                // reuse as local cursor
    }
    __syncthreads();
    #pragma unroll
    for (int it = 0; it < EPT; ++it) {
        int b = d[it] >> 7;
        int slot = atomicAdd(&lcnt[b], 1);
        bucket[lbase[b] + slot] = ((unsigned)(d[it] & 127) << 17) | (unsigned)s[it];
    }
}

// Bucket -> node-ordered CSR, one block per bucket. Slice is contiguous; the
// scatter happens entirely in a 10KB LDS window, then csr/offs are written
// coalesced. No fine-grained global scatter anywhere.
__global__ __launch_bounds__(256) void bucket2csr_kernel(const unsigned* __restrict__ bucket,
                                                         const int* __restrict__ gbase,
                                                         int* __restrict__ offs,
                                                         int* __restrict__ csr) {
    __shared__ int lcnt[BKT];
    __shared__ int ls[BKT];
    __shared__ int lcur[BKT];
    __shared__ int lcsr[CAP];
    int b = blockIdx.x;
    int t = threadIdx.x;
    int e0 = gbase[b], e1 = gbase[b + 1];
    int len = e1 - e0;
    if (t < BKT) lcnt[t] = 0;
    __syncthreads();
    for (int i = e0 + t; i < e1; i += 256)
        atomicAdd(&lcnt[bucket[i] >> 17], 1);
    __syncthreads();
    if (t < BKT) ls[t] = lcnt[t];
    __syncthreads();
    #pragma unroll
    for (int off = 1; off < BKT; off <<= 1) {
        int u = (t < BKT && t >= off) ? ls[t - off] : 0;
        __syncthreads();
        if (t < BKT) ls[t] += u;
        __syncthreads();
    }
    if (t < BKT) {
        int ex = ls[t] - lcnt[t];           // exclusive, slice-local
        lcur[t] = ex;
        int n = b * BKT + t;
        if (n < NN) offs[n] = e0 + ex;
    }
    __syncthreads();
    if (len <= CAP) {
        for (int i = e0 + t; i < e1; i += 256) {
            unsigned p = bucket[i];
            int pos = atomicAdd(&lcur[p >> 17], 1);
            lcsr[pos] = (int)(p & 0x1FFFFu);
        }
        __syncthreads();
        for (int i = t; i < len; i += 256) csr[e0 + i] = lcsr[i];
    } else {                                 // statistically unreachable guard
        for (int i = e0 + t; i < e1; i += 256) {
            unsigned p = bucket[i];
            int pos = atomicAdd(&lcur[p >> 17], 1);
            csr[e0 + pos] = (int)(p & 0x1FFFFu);
        }
    }
}

// Fused per-step kernel: 8 threads per node. h = half (alternating edges),
// q = quarter of the 16-dim row. gather-sum -> merge halves (shfl 4) ->
// exchange quarters (shfl 1..3) -> 16x16 matvec -> Euler -> renorm -> store.
// NOTE: xin and xout MUST be different buffers (gather reads neighbor rows).
__global__ __launch_bounds__(256) void step_kernel(const float4* __restrict__ x4in,
                                                   const int* __restrict__ offs,
                                                   const int* __restrict__ csr,
                                                   const float* __restrict__ Wc,
                                                   const float* __restrict__ bc,
                                                   const float* __restrict__ b_out,
                                                   float4* __restrict__ x4out) {
    __shared__ float sWc[256];
    __shared__ float sbc[16];
    __shared__ float sb[16];
    int t = threadIdx.x;
    sWc[t] = Wc[t];
    if (t < 16) { sbc[t] = bc[t]; sb[t] = b_out[t]; }
    __syncthreads();

    int tid = blockIdx.x * 256 + t;
    int n = tid >> 3;
    int h = (tid >> 2) & 1;
    int q = tid & 3;
    if (n >= NN) return;

    int o0 = offs[n];
    int o1 = offs[n + 1];

    float4 acc = make_float4(0.f, 0.f, 0.f, 0.f);
    for (int e = o0 + h; e < o1; e += 2) {
        int s = csr[e];
        float4 v = x4in[s * 4 + q];
        acc.x += v.x; acc.y += v.y; acc.z += v.z; acc.w += v.w;
    }
    // merge the two halves (lanes differing in bit 2)
    acc.x += __shfl_xor(acc.x, 4);
    acc.y += __shfl_xor(acc.y, 4);
    acc.z += __shfl_xor(acc.z, 4);
    acc.w += __shfl_xor(acc.w, 4);

    // assemble full 16-dim aggregate across the 4-lane q-group
    float a[16];
    a[4 * q + 0] = acc.x; a[4 * q + 1] = acc.y; a[4 * q + 2] = acc.z; a[4 * q + 3] = acc.w;
    #pragma unroll
    for (int m = 1; m < 4; ++m) {
        int p = q ^ m;
        a[4 * p + 0] = __shfl_xor(acc.x, m);
        a[4 * p + 1] = __shfl_xor(acc.y, m);
        a[4 * p + 2] = __shfl_xor(acc.z, m);
        a[4 * p + 3] = __shfl_xor(acc.w, m);
    }

    float dg = (float)(o1 - o0);

    // this lane's 4 output columns j = 4q..4q+3 (computed redundantly by both halves)
    float o[4];
    #pragma unroll
    for (int jj = 0; jj < 4; ++jj) {
        int j = 4 * q + jj;
        float s = dg * sbc[j] + sb[j];
        #pragma unroll
        for (int k = 0; k < 16; ++k)
            s = fmaf(a[k], sWc[k * 16 + j], s);
        o[jj] = s;
    }

    float4 xv = x4in[(size_t)n * 4 + q];
    float xn[4];
    xn[0] = xv.x + DT_C * o[0];
    xn[1] = xv.y + DT_C * o[1];
    xn[2] = xv.z + DT_C * o[2];
    xn[3] = xv.w + DT_C * o[3];

    // pol columns 3..6: q==0 holds col 3 (xn[3]); q==1 holds cols 4,5,6 (xn[0..2])
    float ssp = 0.f;
    if (q == 0) ssp = xn[3] * xn[3];
    if (q == 1) ssp = xn[0] * xn[0] + xn[1] * xn[1] + xn[2] * xn[2];
    ssp += __shfl_xor(ssp, 1);
    ssp += __shfl_xor(ssp, 2);
    float sc = 1.0f / fmaxf(sqrtf(ssp), EPS_C);
    if (q == 0) xn[3] *= sc;
    if (q == 1) { xn[0] *= sc; xn[1] *= sc; xn[2] *= sc; }

    if (h == 0) {
        float4 outv = make_float4(xn[0], xn[1], xn[2], xn[3]);
        x4out[(size_t)n * 4 + q] = outv;
    }
}

extern "C" void kernel_launch(void* const* d_in, const int* in_sizes, int n_in,
                              void* d_out, int out_size, void* d_ws, size_t ws_size,
                              hipStream_t stream) {
    const float* x0    = (const float*)d_in[0];
    const int*   ei    = (const int*)d_in[1];   // (2, NE): row0=src, row1=dst
    const float* W_msg = (const float*)d_in[2];
    const float* b_msg = (const float*)d_in[3];
    const float* W_out = (const float*)d_in[4];
    const float* b_out = (const float*)d_in[5];

    float* X = (float*)d_out;                   // final state buffer (ping-pong B1)

    // ws layout: region0 = Y (steps) ALIASED with bucket (CSR build; dead
    // before step 1 writes Y). Then csr, offs, bcnt, gbase, gcur, Wc, bc.
    float*    Y      = (float*)d_ws;            // 6.4 MB
    unsigned* bucket = (unsigned*)d_ws;         // alias, 6.4 MB
    int*      csr    = (int*)(Y + (size_t)NN * IN_DIM);
    int*      offs   = csr + NE;                // NN+1
    int*      bcnt   = offs + NN + 1;           // NB
    int*      gbase  = bcnt + NB;               // NB+1
    int*      gcur   = gbase + NB + 1;          // NB
    float*    Wc     = (float*)(gcur + NB);     // 256
    float*    bc     = Wc + 256;                // 16

    const int* src = ei;
    const int* dst = ei + NE;

    compute_wc_kernel<<<1, 256, 0, stream>>>(W_msg, b_msg, W_out, Wc, bc);
    (void)hipMemsetAsync(bcnt, 0, (size_t)NB * sizeof(int), stream);
    hist782_kernel<<<NBB, 256, 0, stream>>>(dst, bcnt);
    scan782_kernel<<<1, 1024, 0, stream>>>(bcnt, gbase, gcur, offs);
    bucketA_kernel<<<NBB, 256, 0, stream>>>(src, dst, gcur, bucket);
    bucket2csr_kernel<<<NB, 256, 0, stream>>>(bucket, gbase, offs, csr);

    const int step_threads = NN * 8;
    const int step_blocks = (step_threads + 255) / 256;

    // 4 steps, ping-pong: x0 -> Y -> X -> Y -> X (final lands in d_out)
    const float* bufs_in[4]  = { x0, Y, X, Y };
    float*       bufs_out[4] = { Y,  X, Y, X };
    for (int s = 0; s < 4; ++s) {
        step_kernel<<<step_blocks, 256, 0, stream>>>(
            (const float4*)bufs_in[s], offs, csr, Wc, bc, b_out,
            (float4*)bufs_out[s]);
    }
}

// Round 11
// 186.149 us; speedup vs baseline: 4.0238x; 1.0501x over previous
//
#include <hip/hip_runtime.h>

#define NN 100000
#define NE 1600000
#define IN_DIM 16
#define MSG_DIM 128
#define DT_C 0.1f
#define EPS_C 1e-8f
#define BKT 128                          // dst-nodes per bucket
#define NB ((NN + BKT - 1) / BKT)        // 782 buckets
#define EPB 6400                         // edges per bucketing block
#define NBB (NE / EPB)                   // 250 (exact)
#define EPT (EPB / 256)                  // 25 edges per thread
#define CAP 2560                         // LDS csr-slice capacity (mean 2048, sd 45)

__device__ __forceinline__ float b2f(unsigned short u) {
    union { unsigned int i; float f; } v;
    v.i = (unsigned int)u << 16;
    return v.f;
}
__device__ __forceinline__ unsigned short f2b(float f) {
    union { float f; unsigned int i; } v;
    v.f = f;
    unsigned int b = v.i + 0x7FFFu + ((v.i >> 16) & 1u);   // round-nearest-even
    return (unsigned short)(b >> 16);
}

// Wc = W_msg @ W_out (16x16), bc = b_msg @ W_out (16)
__global__ void compute_wc_kernel(const float* __restrict__ W_msg,
                                  const float* __restrict__ b_msg,
                                  const float* __restrict__ W_out,
                                  float* __restrict__ Wc,
                                  float* __restrict__ bc) {
    int t = threadIdx.x;            // 256 threads
    int i = t >> 4, j = t & 15;
    float s = 0.f;
    for (int k = 0; k < MSG_DIM; ++k)
        s += W_msg[i * MSG_DIM + k] * W_out[k * IN_DIM + j];
    Wc[t] = s;
    if (t < IN_DIM) {
        float sb = 0.f;
        for (int k = 0; k < MSG_DIM; ++k)
            sb += b_msg[k] * W_out[k * IN_DIM + t];
        bc[t] = sb;
    }
}

// f32 state -> bf16 shadow (for L2-resident gathers). 4 elems/thread.
__global__ void cvt_kernel(const float* __restrict__ x, ushort2* __restrict__ xb) {
    int i = blockIdx.x * blockDim.x + threadIdx.x;      // pair index
    if (i * 2 >= NN * IN_DIM) return;
    float2 v = ((const float2*)x)[i];
    xb[i] = make_ushort2(f2b(v.x), f2b(v.y));
}

// Per-bucket histogram: LDS-count then one global atomic per (block, bucket).
__global__ __launch_bounds__(256) void hist782_kernel(const int* __restrict__ dst,
                                                      int* __restrict__ bcnt) {
    __shared__ int lc[NB];
    int t = threadIdx.x;
    for (int j = t; j < NB; j += 256) lc[j] = 0;
    __syncthreads();
    int base = blockIdx.x * EPB + t;
    #pragma unroll
    for (int it = 0; it < EPT; ++it) {
        int d = dst[base + it * 256];
        atomicAdd(&lc[d >> 7], 1);
    }
    __syncthreads();
    for (int j = t; j < NB; j += 256) {
        int c = lc[j];
        if (c) atomicAdd(&bcnt[j], c);
    }
}

// Exclusive scan of the 782 bucket counts (single block); also offs[NN]=NE.
__global__ __launch_bounds__(1024) void scan782_kernel(const int* __restrict__ bcnt,
                                                       int* __restrict__ gbase,
                                                       int* __restrict__ gcur,
                                                       int* __restrict__ offs) {
    __shared__ int sh[1024];
    int t = threadIdx.x;
    int v = (t < NB) ? bcnt[t] : 0;
    sh[t] = v;
    __syncthreads();
    #pragma unroll
    for (int off = 1; off < 1024; off <<= 1) {
        int u = (t >= off) ? sh[t - off] : 0;
        __syncthreads();
        sh[t] += u;
        __syncthreads();
    }
    if (t < NB) {
        int ex = sh[t] - v;
        gbase[t] = ex;
        gcur[t] = ex;
    }
    if (t == 0) { gbase[NB] = NE; offs[NN] = NE; }
}

// Bucketing pass: partition edges by dst-bucket into packed (d_local<<17|src)
// entries. LDS per-bucket count, one global reserve atomic per (block,bucket),
// ~8-entry contiguous runs -> coalesced; edge arrays read exactly once.
__global__ __launch_bounds__(256) void bucketA_kernel(const int* __restrict__ src,
                                                      const int* __restrict__ dst,
                                                      int* __restrict__ gcur,
                                                      unsigned* __restrict__ bucket) {
    __shared__ int lcnt[NB];
    __shared__ int lbase[NB];
    int t = threadIdx.x;
    for (int j = t; j < NB; j += 256) lcnt[j] = 0;
    __syncthreads();

    int d[EPT], s[EPT];
    int base = blockIdx.x * EPB + t;
    #pragma unroll
    for (int it = 0; it < EPT; ++it) {
        d[it] = dst[base + it * 256];
        s[it] = src[base + it * 256];
    }
    #pragma unroll
    for (int it = 0; it < EPT; ++it) atomicAdd(&lcnt[d[it] >> 7], 1);
    __syncthreads();
    for (int j = t; j < NB; j += 256) {
        int c = lcnt[j];
        lbase[j] = c ? atomicAdd(&gcur[j], c) : 0;
        lcnt[j] = 0;                // reuse as local cursor
    }
    __syncthreads();
    #pragma unroll
    for (int it = 0; it < EPT; ++it) {
        int b = d[it] >> 7;
        int slot = atomicAdd(&lcnt[b], 1);
        bucket[lbase[b] + slot] = ((unsigned)(d[it] & 127) << 17) | (unsigned)s[it];
    }
}

// Bucket -> node-ordered CSR, one block per bucket. Scatter confined to a
// 10KB LDS window; csr/offs written coalesced.
__global__ __launch_bounds__(256) void bucket2csr_kernel(const unsigned* __restrict__ bucket,
                                                         const int* __restrict__ gbase,
                                                         int* __restrict__ offs,
                                                         int* __restrict__ csr) {
    __shared__ int lcnt[BKT];
    __shared__ int ls[BKT];
    __shared__ int lcur[BKT];
    __shared__ int lcsr[CAP];
    int b = blockIdx.x;
    int t = threadIdx.x;
    int e0 = gbase[b], e1 = gbase[b + 1];
    int len = e1 - e0;
    if (t < BKT) lcnt[t] = 0;
    __syncthreads();
    for (int i = e0 + t; i < e1; i += 256)
        atomicAdd(&lcnt[bucket[i] >> 17], 1);
    __syncthreads();
    if (t < BKT) ls[t] = lcnt[t];
    __syncthreads();
    #pragma unroll
    for (int off = 1; off < BKT; off <<= 1) {
        int u = (t < BKT && t >= off) ? ls[t - off] : 0;
        __syncthreads();
        if (t < BKT) ls[t] += u;
        __syncthreads();
    }
    if (t < BKT) {
        int ex = ls[t] - lcnt[t];           // exclusive, slice-local
        lcur[t] = ex;
        int n = b * BKT + t;
        if (n < NN) offs[n] = e0 + ex;
    }
    __syncthreads();
    if (len <= CAP) {
        for (int i = e0 + t; i < e1; i += 256) {
            unsigned p = bucket[i];
            int pos = atomicAdd(&lcur[p >> 17], 1);
            lcsr[pos] = (int)(p & 0x1FFFFu);
        }
        __syncthreads();
        for (int i = t; i < len; i += 256) csr[e0 + i] = lcsr[i];
    } else {                                 // statistically unreachable guard
        for (int i = e0 + t; i < e1; i += 256) {
            unsigned p = bucket[i];
            int pos = atomicAdd(&lcur[p >> 17], 1);
            csr[e0 + pos] = (int)(p & 0x1FFFFu);
        }
    }
}

// Fused per-step kernel: 8 threads per node. h = half (alternating edges),
// q = quarter of the 16-dim row. Neighbor gathers read the BF16 shadow
// (3.2MB -> L2-resident per XCD); own row + Euler update stay fp32.
// Writes both the fp32 next state and its bf16 shadow.
// NOTE: xin/xout (and shadows) MUST be different buffers.
__global__ __launch_bounds__(256) void step_kernel(const float4* __restrict__ x4in,
                                                   const ushort4* __restrict__ xbin,
                                                   const int* __restrict__ offs,
                                                   const int* __restrict__ csr,
                                                   const float* __restrict__ Wc,
                                                   const float* __restrict__ bc,
                                                   const float* __restrict__ b_out,
                                                   float4* __restrict__ x4out,
                                                   ushort4* __restrict__ xbout) {
    __shared__ float sWc[256];
    __shared__ float sbc[16];
    __shared__ float sb[16];
    int t = threadIdx.x;
    sWc[t] = Wc[t];
    if (t < 16) { sbc[t] = bc[t]; sb[t] = b_out[t]; }
    __syncthreads();

    int tid = blockIdx.x * 256 + t;
    int n = tid >> 3;
    int h = (tid >> 2) & 1;
    int q = tid & 3;
    if (n >= NN) return;

    int o0 = offs[n];
    int o1 = offs[n + 1];

    float ax = 0.f, ay = 0.f, az = 0.f, aw = 0.f;
    for (int e = o0 + h; e < o1; e += 2) {
        int s = csr[e];
        ushort4 v = xbin[s * 4 + q];        // 8B: 4 bf16 of the 16-dim row
        ax += b2f(v.x); ay += b2f(v.y); az += b2f(v.z); aw += b2f(v.w);
    }
    // merge the two halves (lanes differing in bit 2)
    ax += __shfl_xor(ax, 4);
    ay += __shfl_xor(ay, 4);
    az += __shfl_xor(az, 4);
    aw += __shfl_xor(aw, 4);

    // assemble full 16-dim aggregate across the 4-lane q-group
    float a[16];
    a[4 * q + 0] = ax; a[4 * q + 1] = ay; a[4 * q + 2] = az; a[4 * q + 3] = aw;
    #pragma unroll
    for (int m = 1; m < 4; ++m) {
        int p = q ^ m;
        a[4 * p + 0] = __shfl_xor(ax, m);
        a[4 * p + 1] = __shfl_xor(ay, m);
        a[4 * p + 2] = __shfl_xor(az, m);
        a[4 * p + 3] = __shfl_xor(aw, m);
    }

    float dg = (float)(o1 - o0);

    // this lane's 4 output columns j = 4q..4q+3 (computed redundantly by both halves)
    float o[4];
    #pragma unroll
    for (int jj = 0; jj < 4; ++jj) {
        int j = 4 * q + jj;
        float s = dg * sbc[j] + sb[j];
        #pragma unroll
        for (int k = 0; k < 16; ++k)
            s = fmaf(a[k], sWc[k * 16 + j], s);
        o[jj] = s;
    }

    float4 xv = x4in[(size_t)n * 4 + q];
    float xn[4];
    xn[0] = xv.x + DT_C * o[0];
    xn[1] = xv.y + DT_C * o[1];
    xn[2] = xv.z + DT_C * o[2];
    xn[3] = xv.w + DT_C * o[3];

    // pol columns 3..6: q==0 holds col 3 (xn[3]); q==1 holds cols 4,5,6 (xn[0..2])
    float ssp = 0.f;
    if (q == 0) ssp = xn[3] * xn[3];
    if (q == 1) ssp = xn[0] * xn[0] + xn[1] * xn[1] + xn[2] * xn[2];
    ssp += __shfl_xor(ssp, 1);
    ssp += __shfl_xor(ssp, 2);
    float sc = 1.0f / fmaxf(sqrtf(ssp), EPS_C);
    if (q == 0) xn[3] *= sc;
    if (q == 1) { xn[0] *= sc; xn[1] *= sc; xn[2] *= sc; }

    if (h == 0) {
        x4out[(size_t)n * 4 + q] = make_float4(xn[0], xn[1], xn[2], xn[3]);
        xbout[(size_t)n * 4 + q] = make_ushort4(f2b(xn[0]), f2b(xn[1]),
                                                f2b(xn[2]), f2b(xn[3]));
    }
}

extern "C" void kernel_launch(void* const* d_in, const int* in_sizes, int n_in,
                              void* d_out, int out_size, void* d_ws, size_t ws_size,
                              hipStream_t stream) {
    const float* x0    = (const float*)d_in[0];
    const int*   ei    = (const int*)d_in[1];   // (2, NE): row0=src, row1=dst
    const float* W_msg = (const float*)d_in[2];
    const float* b_msg = (const float*)d_in[3];
    const float* W_out = (const float*)d_in[4];
    const float* b_out = (const float*)d_in[5];

    float* X = (float*)d_out;                   // final state buffer (ping-pong B1)

    // ws layout (no aliasing; ws is large): Y (NN*16 f), xb0/xb1 (NN*16 bf16),
    // bucket (NE u32), csr (NE int), offs (NN+1), bcnt, gbase, gcur, Wc, bc
    float*          Y      = (float*)d_ws;
    unsigned short* xb0    = (unsigned short*)(Y + (size_t)NN * IN_DIM);
    unsigned short* xb1    = xb0 + (size_t)NN * IN_DIM;
    unsigned*       bucket = (unsigned*)(xb1 + (size_t)NN * IN_DIM);
    int*            csr    = (int*)(bucket + NE);
    int*            offs   = csr + NE;          // NN+1
    int*            bcnt   = offs + NN + 1;     // NB
    int*            gbase  = bcnt + NB;         // NB+1
    int*            gcur   = gbase + NB + 1;    // NB
    float*          Wc     = (float*)(gcur + NB);
    float*          bc     = Wc + 256;

    const int* src = ei;
    const int* dst = ei + NE;

    compute_wc_kernel<<<1, 256, 0, stream>>>(W_msg, b_msg, W_out, Wc, bc);
    cvt_kernel<<<(NN * IN_DIM / 2 + 255) / 256, 256, 0, stream>>>(x0, (ushort2*)xb0);
    (void)hipMemsetAsync(bcnt, 0, (size_t)NB * sizeof(int), stream);
    hist782_kernel<<<NBB, 256, 0, stream>>>(dst, bcnt);
    scan782_kernel<<<1, 1024, 0, stream>>>(bcnt, gbase, gcur, offs);
    bucketA_kernel<<<NBB, 256, 0, stream>>>(src, dst, gcur, bucket);
    bucket2csr_kernel<<<NB, 256, 0, stream>>>(bucket, gbase, offs, csr);

    const int step_threads = NN * 8;
    const int step_blocks = (step_threads + 255) / 256;

    // 4 steps, ping-pong fp32: x0 -> Y -> X -> Y -> X ; bf16 shadow: xb0->xb1->xb0->...
    const float*          fin[4]  = { x0,  Y,   X,   Y  };
    float*                fout[4] = { Y,   X,   Y,   X  };
    const unsigned short* bin[4]  = { xb0, xb1, xb0, xb1 };
    unsigned short*       bout[4] = { xb1, xb0, xb1, xb0 };
    for (int s = 0; s < 4; ++s) {
        step_kernel<<<step_blocks, 256, 0, stream>>>(
            (const float4*)fin[s], (const ushort4*)bin[s], offs, csr,
            Wc, bc, b_out, (float4*)fout[s], (ushort4*)bout[s]);
    }
}

// Round 12
// 128.871 us; speedup vs baseline: 5.8123x; 1.4445x over previous
//
#include <hip/hip_runtime.h>

#define NN 100000
#define NE 1600000
#define IN_DIM 16
#define MSG_DIM 128
#define DT_C 0.1f
#define EPS_C 1e-8f
#define BKT 128                          // dst-nodes per bucket
#define NB ((NN + BKT - 1) / BKT)        // 782 buckets
#define EPB 6400                         // edges per bucketing block
#define NBB (NE / EPB)                   // 250 (exact)
#define EPT (EPB / 256)                  // 25 edges per thread
#define CAPB 4096                        // padded bucket region (mean 2048, 45 sigma)
#define CAP 2560                         // LDS csr-slice capacity in bucket2csr

__device__ __forceinline__ float blo(unsigned c) { return __uint_as_float(c << 16); }
__device__ __forceinline__ float bhi(unsigned c) { return __uint_as_float(c & 0xFFFF0000u); }
__device__ __forceinline__ unsigned short f2b(float f) {
    unsigned int i = __float_as_uint(f);
    unsigned int b = i + 0x7FFFu + ((i >> 16) & 1u);   // round-nearest-even
    return (unsigned short)(b >> 16);
}

// Wc = W_msg @ W_out (16x16), bc = b_msg @ W_out (16)
__global__ void compute_wc_kernel(const float* __restrict__ W_msg,
                                  const float* __restrict__ b_msg,
                                  const float* __restrict__ W_out,
                                  float* __restrict__ Wc,
                                  float* __restrict__ bc) {
    int t = threadIdx.x;            // 256 threads
    int i = t >> 4, j = t & 15;
    float s = 0.f;
    for (int k = 0; k < MSG_DIM; ++k)
        s += W_msg[i * MSG_DIM + k] * W_out[k * IN_DIM + j];
    Wc[t] = s;
    if (t < IN_DIM) {
        float sb = 0.f;
        for (int k = 0; k < MSG_DIM; ++k)
            sb += b_msg[k] * W_out[k * IN_DIM + t];
        bc[t] = sb;
    }
}

// f32 state -> bf16 shadow. Pair layout: low16 = even dim, high16 = odd dim.
__global__ void cvt_kernel(const float* __restrict__ x, unsigned* __restrict__ xb) {
    int i = blockIdx.x * blockDim.x + threadIdx.x;      // pair index
    if (i * 2 >= NN * IN_DIM) return;
    float2 v = ((const float2*)x)[i];
    xb[i] = (unsigned)f2b(v.x) | ((unsigned)f2b(v.y) << 16);
}

// gcur[b] = start of bucket b's PADDED region.
__global__ void init782_kernel(int* __restrict__ gcur) {
    int t = blockIdx.x * blockDim.x + threadIdx.x;
    if (t < NB) gcur[t] = t * CAPB;
}

// Bucketing pass into padded regions: partition edges by dst-bucket as packed
// (d_local<<17 | src). LDS per-bucket count, one global reserve atomic per
// (block,bucket), ~8-entry contiguous runs -> coalesced single edge-pass.
__global__ __launch_bounds__(256) void bucketA_kernel(const int* __restrict__ src,
                                                      const int* __restrict__ dst,
                                                      int* __restrict__ gcur,
                                                      unsigned* __restrict__ bucket) {
    __shared__ int lcnt[NB];
    __shared__ int lbase[NB];
    int t = threadIdx.x;
    for (int j = t; j < NB; j += 256) lcnt[j] = 0;
    __syncthreads();

    int d[EPT], s[EPT];
    int base = blockIdx.x * EPB + t;
    #pragma unroll
    for (int it = 0; it < EPT; ++it) {
        d[it] = dst[base + it * 256];
        s[it] = src[base + it * 256];
    }
    #pragma unroll
    for (int it = 0; it < EPT; ++it) atomicAdd(&lcnt[d[it] >> 7], 1);
    __syncthreads();
    for (int j = t; j < NB; j += 256) {
        int c = lcnt[j];
        lbase[j] = c ? atomicAdd(&gcur[j], c) : 0;
        lcnt[j] = 0;                // reuse as local cursor
    }
    __syncthreads();
    #pragma unroll
    for (int it = 0; it < EPT; ++it) {
        int b = d[it] >> 7;
        int slot = atomicAdd(&lcnt[b], 1);
        bucket[lbase[b] + slot] = ((unsigned)(d[it] & 127) << 17) | (unsigned)s[it];
    }
}

// Exclusive scan of filled counts (gcur[b]-b*CAPB) -> compact bases gbase.
__global__ __launch_bounds__(1024) void scan782_kernel(const int* __restrict__ gcur,
                                                       int* __restrict__ gbase,
                                                       int* __restrict__ offs) {
    __shared__ int sh[1024];
    int t = threadIdx.x;
    int v = (t < NB) ? (gcur[t] - t * CAPB) : 0;
    sh[t] = v;
    __syncthreads();
    #pragma unroll
    for (int off = 1; off < 1024; off <<= 1) {
        int u = (t >= off) ? sh[t - off] : 0;
        __syncthreads();
        sh[t] += u;
        __syncthreads();
    }
    if (t < NB) gbase[t] = sh[t] - v;
    if (t == 0) { gbase[NB] = NE; offs[NN] = NE; }
}

// Padded bucket slice -> node-ordered compact CSR, one block per bucket.
// Scatter confined to a 10KB LDS window; csr/offs written coalesced.
__global__ __launch_bounds__(256) void bucket2csr_kernel(const unsigned* __restrict__ bucket,
                                                         const int* __restrict__ gcur,
                                                         const int* __restrict__ gbase,
                                                         int* __restrict__ offs,
                                                         int* __restrict__ csr) {
    __shared__ int lcnt[BKT];
    __shared__ int ls[BKT];
    __shared__ int lcur[BKT];
    __shared__ int lcsr[CAP];
    int b = blockIdx.x;
    int t = threadIdx.x;
    int p0 = b * CAPB;                  // padded read base
    int len = gcur[b] - p0;             // filled count
    int g0 = gbase[b];                  // compact write base
    if (t < BKT) lcnt[t] = 0;
    __syncthreads();
    for (int i = t; i < len; i += 256)
        atomicAdd(&lcnt[bucket[p0 + i] >> 17], 1);
    __syncthreads();
    if (t < BKT) ls[t] = lcnt[t];
    __syncthreads();
    #pragma unroll
    for (int off = 1; off < BKT; off <<= 1) {
        int u = (t < BKT && t >= off) ? ls[t - off] : 0;
        __syncthreads();
        if (t < BKT) ls[t] += u;
        __syncthreads();
    }
    if (t < BKT) {
        int ex = ls[t] - lcnt[t];       // exclusive, slice-local
        lcur[t] = ex;
        int n = b * BKT + t;
        if (n < NN) offs[n] = g0 + ex;
    }
    __syncthreads();
    if (len <= CAP) {
        for (int i = t; i < len; i += 256) {
            unsigned pk = bucket[p0 + i];
            int pos = atomicAdd(&lcur[pk >> 17], 1);
            lcsr[pos] = (int)(pk & 0x1FFFFu);
        }
        __syncthreads();
        for (int i = t; i < len; i += 256) csr[g0 + i] = lcsr[i];
    } else {                             // statistically unreachable guard
        for (int i = t; i < len; i += 256) {
            unsigned pk = bucket[p0 + i];
            int pos = atomicAdd(&lcur[pk >> 17], 1);
            csr[g0 + pos] = (int)(pk & 0x1FFFFu);
        }
    }
}

// Fused per-step kernel: 8 threads per node = 4 edge-pairs x 2 row-halves.
// Each lane does ONE 16B gather (uint4 = 8 bf16 = half a row) per edge ->
// 3.2M loads/step (half of the 8B scheme). Merge pairs via shfl 2,4; exchange
// halves via shfl 1; per-lane 2 output columns of the 16x16 matvec; Euler +
// pol renorm (cols 3..6) + fp32/bf16 stores. xin != xout required.
__global__ __launch_bounds__(256) void step_kernel(const float2* __restrict__ x2in,
                                                   const uint4* __restrict__ xbin,
                                                   const int* __restrict__ offs,
                                                   const int* __restrict__ csr,
                                                   const float* __restrict__ Wc,
                                                   const float* __restrict__ bc,
                                                   const float* __restrict__ b_out,
                                                   float2* __restrict__ x2out,
                                                   unsigned* __restrict__ xbout) {
    __shared__ float sWc[256];
    __shared__ float sbc[16];
    __shared__ float sb[16];
    int t = threadIdx.x;
    sWc[t] = Wc[t];
    if (t < 16) { sbc[t] = bc[t]; sb[t] = b_out[t]; }
    __syncthreads();

    int tid = blockIdx.x * 256 + t;
    int n = tid >> 3;
    int l = t & 7;                      // lane-in-node
    int p = l >> 1;                     // edge pair 0..3
    int hf = l & 1;                     // row half 0..1
    if (n >= NN) return;

    int o0 = offs[n];
    int o1 = offs[n + 1];

    float acc[8];
    #pragma unroll
    for (int j = 0; j < 8; ++j) acc[j] = 0.f;

    for (int e = o0 + p; e < o1; e += 4) {
        int s = csr[e];
        uint4 v = xbin[s * 2 + hf];     // 16B: 8 bf16 of this half-row
        acc[0] += blo(v.x); acc[1] += bhi(v.x);
        acc[2] += blo(v.y); acc[3] += bhi(v.y);
        acc[4] += blo(v.z); acc[5] += bhi(v.z);
        acc[6] += blo(v.w); acc[7] += bhi(v.w);
    }

    // sum the 4 pairs (same hf lanes differ by xor 2, 4)
    #pragma unroll
    for (int j = 0; j < 8; ++j) {
        acc[j] += __shfl_xor(acc[j], 2);
        acc[j] += __shfl_xor(acc[j], 4);
    }
    // exchange halves (xor 1) -> full 16-dim aggregate, static indexing
    float a[16];
    #pragma unroll
    for (int j = 0; j < 8; ++j) {
        float oth = __shfl_xor(acc[j], 1);
        a[j]     = hf ? oth    : acc[j];
        a[8 + j] = hf ? acc[j] : oth;
    }

    float dg = (float)(o1 - o0);

    // this lane's 2 output columns c0=2l, c0+1
    int c0 = 2 * l;
    float o0f = dg * sbc[c0] + sb[c0];
    float o1f = dg * sbc[c0 + 1] + sb[c0 + 1];
    #pragma unroll
    for (int k = 0; k < 16; ++k) {
        float ak = a[k];
        o0f = fmaf(ak, sWc[k * 16 + c0], o0f);
        o1f = fmaf(ak, sWc[k * 16 + c0 + 1], o1f);
    }

    float2 xv = x2in[(size_t)n * 8 + l];
    float xn0 = xv.x + DT_C * o0f;
    float xn1 = xv.y + DT_C * o1f;

    // pol renorm over cols 3..6
    bool in0 = (c0 >= 3 && c0 <= 6);
    bool in1 = (c0 + 1 >= 3 && c0 + 1 <= 6);
    float ssp = (in0 ? xn0 * xn0 : 0.f) + (in1 ? xn1 * xn1 : 0.f);
    ssp += __shfl_xor(ssp, 1);
    ssp += __shfl_xor(ssp, 2);
    ssp += __shfl_xor(ssp, 4);
    float sc = 1.0f / fmaxf(sqrtf(ssp), EPS_C);
    if (in0) xn0 *= sc;
    if (in1) xn1 *= sc;

    x2out[(size_t)n * 8 + l] = make_float2(xn0, xn1);
    xbout[(size_t)n * 8 + l] = (unsigned)f2b(xn0) | ((unsigned)f2b(xn1) << 16);
}

extern "C" void kernel_launch(void* const* d_in, const int* in_sizes, int n_in,
                              void* d_out, int out_size, void* d_ws, size_t ws_size,
                              hipStream_t stream) {
    const float* x0    = (const float*)d_in[0];
    const int*   ei    = (const int*)d_in[1];   // (2, NE): row0=src, row1=dst
    const float* W_msg = (const float*)d_in[2];
    const float* b_msg = (const float*)d_in[3];
    const float* W_out = (const float*)d_in[4];
    const float* b_out = (const float*)d_in[5];

    float* X = (float*)d_out;                   // final state buffer (ping-pong B1)

    // ws layout: Y (NN*16 f), xb0/xb1 (NN*16 bf16), bucket (NB*CAPB u32,
    // padded), csr (NE), offs (NN+1), gbase (NB+1), gcur (NB), Wc, bc
    float*          Y      = (float*)d_ws;
    unsigned*       xb0    = (unsigned*)(Y + (size_t)NN * IN_DIM);      // NN*8 u32
    unsigned*       xb1    = xb0 + (size_t)NN * (IN_DIM / 2);
    unsigned*       bucket = xb1 + (size_t)NN * (IN_DIM / 2);
    int*            csr    = (int*)(bucket + (size_t)NB * CAPB);
    int*            offs   = csr + NE;          // NN+1
    int*            gbase  = offs + NN + 1;     // NB+1
    int*            gcur   = gbase + NB + 1;    // NB
    float*          Wc     = (float*)(gcur + NB);
    float*          bc     = Wc + 256;

    const int* src = ei;
    const int* dst = ei + NE;

    compute_wc_kernel<<<1, 256, 0, stream>>>(W_msg, b_msg, W_out, Wc, bc);
    cvt_kernel<<<(NN * IN_DIM / 2 + 255) / 256, 256, 0, stream>>>(x0, xb0);
    init782_kernel<<<(NB + 255) / 256, 256, 0, stream>>>(gcur);
    bucketA_kernel<<<NBB, 256, 0, stream>>>(src, dst, gcur, bucket);
    scan782_kernel<<<1, 1024, 0, stream>>>(gcur, gbase, offs);
    bucket2csr_kernel<<<NB, 256, 0, stream>>>(bucket, gcur, gbase, offs, csr);

    const int step_threads = NN * 8;
    const int step_blocks = (step_threads + 255) / 256;

    // 4 steps, ping-pong fp32: x0 -> Y -> X -> Y -> X ; bf16 shadow xb0<->xb1
    const float*    fin[4]  = { x0,  Y,   X,   Y  };
    float*          fout[4] = { Y,   X,   Y,   X  };
    const unsigned* bin[4]  = { xb0, xb1, xb0, xb1 };
    unsigned*       bout[4] = { xb1, xb0, xb1, xb0 };
    for (int s = 0; s < 4; ++s) {
        step_kernel<<<step_blocks, 256, 0, stream>>>(
            (const float2*)fin[s], (const uint4*)bin[s], offs, csr,
            Wc, bc, b_out, (float2*)fout[s], bout[s]);
    }
}